// Round 2
// baseline (242.832 us; speedup 1.0000x reference)
//
#include <hip/hip_runtime.h>

#define B_ 16
#define S_ 8192
#define D_ 128
#define C_ 64

// ws float layout:
//   [0, 8192)        cnT[d][c]  (normalized centroids, transposed)
//   [8192, 139264)   ksum  [B][C][D]
//   [139264, 270336) vsum  [B][C][D]
//   [270336, 271360) counts [B][C]
#define WS_CNT_OFF   0
#define WS_KSUM_OFF  8192
#define WS_VSUM_OFF  (8192 + B_*C_*D_)
#define WS_CNTS_OFF  (8192 + 2*B_*C_*D_)

__global__ void normalize_centroids_k(const float* __restrict__ cen,
                                      float* __restrict__ cnT) {
    int tid = threadIdx.x;          // 512 threads, 1 block
    int c = tid >> 3;               // 0..63
    int l = tid & 7;                // 8 lanes per centroid
    float4 v[4];
    float s = 0.f;
#pragma unroll
    for (int q = 0; q < 4; ++q) {
        v[q] = *(const float4*)&cen[c * D_ + l * 16 + q * 4];
        s += v[q].x * v[q].x + v[q].y * v[q].y + v[q].z * v[q].z + v[q].w * v[q].w;
    }
#pragma unroll
    for (int m = 1; m < 8; m <<= 1) s += __shfl_xor(s, m, 8);
    float n = fmaxf(sqrtf(s), 1e-12f);
#pragma unroll
    for (int q = 0; q < 4; ++q) {
        int d = l * 16 + q * 4;
        cnT[(d + 0) * C_ + c] = v[q].x / n;
        cnT[(d + 1) * C_ + c] = v[q].y / n;
        cnT[(d + 2) * C_ + c] = v[q].z / n;
        cnT[(d + 3) * C_ + c] = v[q].w / n;
    }
}

// ---------------- Kernel A: sims + argmax -> assignments (float) -----------
constexpr int A_THREADS = 256;
constexpr int A_TR = 4;                       // rows per thread
constexpr int A_ROWS = (A_THREADS / 8) * A_TR; // 128 rows per block

__global__ __launch_bounds__(A_THREADS, 4) void assign_k(
    const float* __restrict__ keys, const float* __restrict__ mask,
    const float* __restrict__ cnT_g, float* __restrict__ out_asg) {

    __shared__ float cnT[D_ * C_];   // 32 KB

    const int tid = threadIdx.x;
    for (int i = tid; i < D_ * C_; i += A_THREADS) cnT[i] = cnT_g[i];
    __syncthreads();

    const int tc  = tid & 7;          // cluster group: clusters tc*8 .. tc*8+7
    const int trt = tid >> 3;         // 0..31
    const size_t gr0 = (size_t)blockIdx.x * A_ROWS + (size_t)trt * A_TR;
    const float* kbase = keys + gr0 * D_;

    float acc[A_TR][8];
#pragma unroll
    for (int i = 0; i < A_TR; ++i)
#pragma unroll
        for (int j = 0; j < 8; ++j) acc[i][j] = 0.f;

    float4 kc[A_TR];
#pragma unroll
    for (int i = 0; i < A_TR; ++i)
        kc[i] = *(const float4*)(kbase + (size_t)i * D_);

    for (int d0 = 0; d0 < D_; d0 += 4) {
        float4 kn[A_TR];
        if (d0 + 4 < D_) {
#pragma unroll
            for (int i = 0; i < A_TR; ++i)
                kn[i] = *(const float4*)(kbase + (size_t)i * D_ + d0 + 4);
        }
#pragma unroll
        for (int dd = 0; dd < 4; ++dd) {
            const float4 c0 = *(const float4*)&cnT[(d0 + dd) * C_ + tc * 8];
            const float4 c1 = *(const float4*)&cnT[(d0 + dd) * C_ + tc * 8 + 4];
            const float cw[8] = {c0.x, c0.y, c0.z, c0.w, c1.x, c1.y, c1.z, c1.w};
#pragma unroll
            for (int i = 0; i < A_TR; ++i) {
                const float kv = dd == 0 ? kc[i].x : dd == 1 ? kc[i].y
                               : dd == 2 ? kc[i].z : kc[i].w;
#pragma unroll
                for (int j = 0; j < 8; ++j)
                    acc[i][j] = fmaf(kv, cw[j], acc[i][j]);
            }
        }
#pragma unroll
        for (int i = 0; i < A_TR; ++i) kc[i] = kn[i];
    }

    // per-row argmax across 8 tc lanes; first-max-index tie-break (jnp.argmax)
#pragma unroll
    for (int i = 0; i < A_TR; ++i) {
        float bv = acc[i][0];
        int bi = tc * 8;
#pragma unroll
        for (int j = 1; j < 8; ++j)
            if (acc[i][j] > bv) { bv = acc[i][j]; bi = tc * 8 + j; }
#pragma unroll
        for (int m = 1; m < 8; m <<= 1) {
            float ov = __shfl_xor(bv, m, 8);
            int   oi = __shfl_xor(bi, m, 8);
            if (ov > bv || (ov == bv && oi < bi)) { bv = ov; bi = oi; }
        }
        if (tc == 0) {
            float mv = mask[gr0 + i];
            out_asg[gr0 + i] = (float)((mv != 0.f) ? bi : 0);
        }
    }
}

// ---------------- Kernel B: accumulate per-cluster sums --------------------
constexpr int ACC_THREADS = 512;
constexpr int ACC_ROWS   = 256;    // rows per block

__global__ __launch_bounds__(ACC_THREADS, 4) void accum_k(
    const float* __restrict__ keys, const float* __restrict__ values,
    const float* __restrict__ mask, const float* __restrict__ out_asg,
    float* __restrict__ g_ksum, float* __restrict__ g_vsum,
    float* __restrict__ g_cnt) {

    __shared__ float accK[C_ * D_];   // 32 KB
    __shared__ float accV[C_ * D_];   // 32 KB
    __shared__ float cntL[C_];

    const int tid = threadIdx.x;
    for (int i = tid; i < C_ * D_; i += ACC_THREADS) { accK[i] = 0.f; accV[i] = 0.f; }
    if (tid < C_) cntL[tid] = 0.f;
    __syncthreads();

    const int bid = blockIdx.x;
    const int batch = bid >> 5;                 // 32 blocks per batch
    const int srow0 = (bid & 31) * ACC_ROWS;
    const size_t rbase = (size_t)batch * S_ + srow0;
    const float* kb = keys + rbase * D_;
    const float* vb = values + rbase * D_;

    const int t = tid & 127;       // dim
    const int g = tid >> 7;        // row group 0..3

    for (int rr = 0; rr < ACC_ROWS; rr += 4) {
        const int row = rr + g;
        const float mv = mask[rbase + row];
        if (mv != 0.f) {
            const int a = (int)out_asg[rbase + row];
            atomicAdd(&accK[a * D_ + t], kb[(size_t)row * D_ + t]);
            atomicAdd(&accV[a * D_ + t], vb[(size_t)row * D_ + t]);
            if (t == 0) atomicAdd(&cntL[a], 1.f);
        }
    }
    __syncthreads();

    float* gks = g_ksum + (size_t)batch * C_ * D_;
    float* gvs = g_vsum + (size_t)batch * C_ * D_;
    for (int i = tid; i < C_ * D_; i += ACC_THREADS) {
        atomicAdd(&gks[i], accK[i]);
        atomicAdd(&gvs[i], accV[i]);
    }
    if (tid < C_) atomicAdd(&g_cnt[batch * C_ + tid], cntL[tid]);
}

// ---------------- Kernel C: finalize --------------------------------------
__global__ void finalize_k(const float* __restrict__ ws,
                           const float* __restrict__ cen,
                           float* __restrict__ out) {
    int idx = blockIdx.x * blockDim.x + threadIdx.x;   // < B*C*D
    const float* ksum = ws + WS_KSUM_OFF;
    const float* vsum = ws + WS_VSUM_OFF;
    const float* cnt  = ws + WS_CNTS_OFF;
    int bc = idx >> 7;             // b*64 + c
    int cd = idx & (C_ * D_ - 1);  // c*128 + d
    float n = cnt[bc];
    float cc, cv;
    if (n > 0.f) {
        cc = ksum[idx] / n;
        cv = vsum[idx] / n;
    } else {
        cc = cen[cd];
        cv = 0.f;
    }
    out[idx] = cc;
    out[B_ * C_ * D_ + idx] = cv;
}

extern "C" void kernel_launch(void* const* d_in, const int* in_sizes, int n_in,
                              void* d_out, int out_size, void* d_ws, size_t ws_size,
                              hipStream_t stream) {
    const float* keys   = (const float*)d_in[0];
    const float* values = (const float*)d_in[1];
    const float* mask   = (const float*)d_in[2];
    const float* cen    = (const float*)d_in[3];
    float* ws  = (float*)d_ws;
    float* out = (float*)d_out;
    float* out_asg = out + 2 * B_ * C_ * D_;

    // zero the accumulator region (ksum, vsum, counts) every call
    hipMemsetAsync(ws + WS_KSUM_OFF, 0,
                   (size_t)(2 * B_ * C_ * D_ + B_ * C_) * sizeof(float), stream);

    normalize_centroids_k<<<1, 512, 0, stream>>>(cen, ws + WS_CNT_OFF);

    assign_k<<<(B_ * S_) / A_ROWS, A_THREADS, 0, stream>>>(
        keys, mask, ws + WS_CNT_OFF, out_asg);

    accum_k<<<(B_ * S_) / ACC_ROWS, ACC_THREADS, 0, stream>>>(
        keys, values, mask, out_asg,
        ws + WS_KSUM_OFF, ws + WS_VSUM_OFF, ws + WS_CNTS_OFF);

    finalize_k<<<(B_ * C_ * D_) / 256, 256, 0, stream>>>(ws, cen, out);
}

// Round 3
// 232.917 us; speedup vs baseline: 1.0426x; 1.0426x over previous
//
#include <hip/hip_runtime.h>

#define B_ 16
#define S_ 8192
#define D_ 128
#define C_ 64

// ws float layout:
//   [0, 8192)        cnT[d][c]  (normalized centroids, transposed)
//   [8192, 139264)   ksum  [B][C][D]
//   [139264, 270336) vsum  [B][C][D]
//   [270336, 271360) counts [B][C]
#define WS_CNT_OFF   0
#define WS_KSUM_OFF  8192
#define WS_VSUM_OFF  (8192 + B_*C_*D_)
#define WS_CNTS_OFF  (8192 + 2*B_*C_*D_)

__global__ void normalize_centroids_k(const float* __restrict__ cen,
                                      float* __restrict__ cnT) {
    int tid = threadIdx.x;          // 512 threads, 1 block
    int c = tid >> 3;               // 0..63
    int l = tid & 7;                // 8 lanes per centroid
    float4 v[4];
    float s = 0.f;
#pragma unroll
    for (int q = 0; q < 4; ++q) {
        v[q] = *(const float4*)&cen[c * D_ + l * 16 + q * 4];
        s += v[q].x * v[q].x + v[q].y * v[q].y + v[q].z * v[q].z + v[q].w * v[q].w;
    }
#pragma unroll
    for (int m = 1; m < 8; m <<= 1) s += __shfl_xor(s, m, 8);
    float n = fmaxf(sqrtf(s), 1e-12f);
#pragma unroll
    for (int q = 0; q < 4; ++q) {
        int d = l * 16 + q * 4;
        cnT[(d + 0) * C_ + c] = v[q].x / n;
        cnT[(d + 1) * C_ + c] = v[q].y / n;
        cnT[(d + 2) * C_ + c] = v[q].z / n;
        cnT[(d + 3) * C_ + c] = v[q].w / n;
    }
}

// ---------------- Kernel A: sims + argmax -> assignments (float) -----------
constexpr int A_THREADS = 256;
constexpr int A_TR = 4;                       // rows per thread
constexpr int A_ROWS = (A_THREADS / 8) * A_TR; // 128 rows per block

__global__ __launch_bounds__(A_THREADS, 4) void assign_k(
    const float* __restrict__ keys, const float* __restrict__ mask,
    const float* __restrict__ cnT_g, float* __restrict__ out_asg) {

    __shared__ float cnT[D_ * C_];   // 32 KB

    const int tid = threadIdx.x;
    for (int i = tid; i < D_ * C_; i += A_THREADS) cnT[i] = cnT_g[i];
    __syncthreads();

    const int tc  = tid & 7;          // cluster group: clusters tc*8 .. tc*8+7
    const int trt = tid >> 3;         // 0..31
    const size_t gr0 = (size_t)blockIdx.x * A_ROWS + (size_t)trt * A_TR;
    const float* kbase = keys + gr0 * D_;

    float acc[A_TR][8];
#pragma unroll
    for (int i = 0; i < A_TR; ++i)
#pragma unroll
        for (int j = 0; j < 8; ++j) acc[i][j] = 0.f;

    float4 kc[A_TR];
#pragma unroll
    for (int i = 0; i < A_TR; ++i)
        kc[i] = *(const float4*)(kbase + (size_t)i * D_);

    for (int d0 = 0; d0 < D_; d0 += 4) {
        float4 kn[A_TR];
        if (d0 + 4 < D_) {
#pragma unroll
            for (int i = 0; i < A_TR; ++i)
                kn[i] = *(const float4*)(kbase + (size_t)i * D_ + d0 + 4);
        }
#pragma unroll
        for (int dd = 0; dd < 4; ++dd) {
            const float4 c0 = *(const float4*)&cnT[(d0 + dd) * C_ + tc * 8];
            const float4 c1 = *(const float4*)&cnT[(d0 + dd) * C_ + tc * 8 + 4];
            const float cw[8] = {c0.x, c0.y, c0.z, c0.w, c1.x, c1.y, c1.z, c1.w};
#pragma unroll
            for (int i = 0; i < A_TR; ++i) {
                const float kv = dd == 0 ? kc[i].x : dd == 1 ? kc[i].y
                               : dd == 2 ? kc[i].z : kc[i].w;
#pragma unroll
                for (int j = 0; j < 8; ++j)
                    acc[i][j] = fmaf(kv, cw[j], acc[i][j]);
            }
        }
#pragma unroll
        for (int i = 0; i < A_TR; ++i) kc[i] = kn[i];
    }

    // per-row argmax across 8 tc lanes; first-max-index tie-break (jnp.argmax)
#pragma unroll
    for (int i = 0; i < A_TR; ++i) {
        float bv = acc[i][0];
        int bi = tc * 8;
#pragma unroll
        for (int j = 1; j < 8; ++j)
            if (acc[i][j] > bv) { bv = acc[i][j]; bi = tc * 8 + j; }
#pragma unroll
        for (int m = 1; m < 8; m <<= 1) {
            float ov = __shfl_xor(bv, m, 8);
            int   oi = __shfl_xor(bi, m, 8);
            if (ov > bv || (ov == bv && oi < bi)) { bv = ov; bi = oi; }
        }
        if (tc == 0) {
            float mv = mask[gr0 + i];
            out_asg[gr0 + i] = (float)((mv != 0.f) ? bi : 0);
        }
    }
}

// ---------------- Kernel B: accumulate per-cluster sums --------------------
// 512 threads, 256 rows/block, grid 512 (2 blocks/CU, 16 waves/CU).
// All global load addresses are pure loop-index functions; the only
// data-dependent part is the LDS atomic address, read from LDS cid[].
constexpr int ACC_THREADS = 512;
constexpr int ACC_ROWS   = 256;
constexpr int ACC_NIT    = ACC_ROWS / 8;   // 32 iterations, 8 rows each

__global__ __launch_bounds__(ACC_THREADS, 2) void accum_k(
    const float* __restrict__ keys, const float* __restrict__ values,
    const float* __restrict__ mask, const float* __restrict__ out_asg,
    float* __restrict__ g_ksum, float* __restrict__ g_vsum,
    float* __restrict__ g_cnt) {

    __shared__ float accK[C_ * D_];   // 32 KB
    __shared__ float accV[C_ * D_];   // 32 KB
    __shared__ float cntL[C_];
    __shared__ short cid[ACC_ROWS];

    const int tid = threadIdx.x;
    for (int i = tid; i < C_ * D_; i += ACC_THREADS) { accK[i] = 0.f; accV[i] = 0.f; }
    if (tid < C_) cntL[tid] = 0.f;
    __syncthreads();

    const int bid = blockIdx.x;
    const int batch = bid >> 5;                 // 32 blocks per batch
    const int srow0 = (bid & 31) * ACC_ROWS;
    const size_t rbase = (size_t)batch * S_ + srow0;

    // stage per-row cluster ids (sentinel C_ = masked out)
    if (tid < ACC_ROWS) {
        float mv = mask[rbase + tid];
        int a = (int)out_asg[rbase + tid];
        short s = (mv != 0.f) ? (short)a : (short)C_;
        cid[tid] = s;
        if (s < C_) atomicAdd(&cntL[s], 1.f);
    }
    __syncthreads();

    const int r_off = tid >> 6;          // 0..7  (row within 8-row group)
    const int half  = (tid >> 5) & 1;    // 0 = keys, 1 = values
    const int c4    = tid & 31;          // float4 column
    const float* src = (half ? values : keys) + (rbase + r_off) * D_ + c4 * 4;
    float* acc = half ? accV : accK;

    // depth-2 software pipeline
    float4 cur = *(const float4*)(src);
    float4 nx1 = *(const float4*)(src + (size_t)8 * D_);
    for (int it = 0; it < ACC_NIT; ++it) {
        float4 nx2 = cur;
        if (it + 2 < ACC_NIT)
            nx2 = *(const float4*)(src + (size_t)(it + 2) * 8 * D_);
        const int a = cid[it * 8 + r_off];
        if (a < C_) {
            float* p = &acc[a * D_ + c4 * 4];
            atomicAdd(p + 0, cur.x);
            atomicAdd(p + 1, cur.y);
            atomicAdd(p + 2, cur.z);
            atomicAdd(p + 3, cur.w);
        }
        cur = nx1; nx1 = nx2;
    }
    __syncthreads();

    // flush block partials to global
    float* gks = g_ksum + (size_t)batch * C_ * D_;
    float* gvs = g_vsum + (size_t)batch * C_ * D_;
    for (int i = tid; i < C_ * D_; i += ACC_THREADS) {
        atomicAdd(&gks[i], accK[i]);
        atomicAdd(&gvs[i], accV[i]);
    }
    if (tid < C_) atomicAdd(&g_cnt[batch * C_ + tid], cntL[tid]);
}

// ---------------- Kernel C: finalize --------------------------------------
__global__ void finalize_k(const float* __restrict__ ws,
                           const float* __restrict__ cen,
                           float* __restrict__ out) {
    int idx = blockIdx.x * blockDim.x + threadIdx.x;   // < B*C*D
    const float* ksum = ws + WS_KSUM_OFF;
    const float* vsum = ws + WS_VSUM_OFF;
    const float* cnt  = ws + WS_CNTS_OFF;
    int bc = idx >> 7;             // b*64 + c
    int cd = idx & (C_ * D_ - 1);  // c*128 + d
    float n = cnt[bc];
    float cc, cv;
    if (n > 0.f) {
        cc = ksum[idx] / n;
        cv = vsum[idx] / n;
    } else {
        cc = cen[cd];
        cv = 0.f;
    }
    out[idx] = cc;
    out[B_ * C_ * D_ + idx] = cv;
}

extern "C" void kernel_launch(void* const* d_in, const int* in_sizes, int n_in,
                              void* d_out, int out_size, void* d_ws, size_t ws_size,
                              hipStream_t stream) {
    const float* keys   = (const float*)d_in[0];
    const float* values = (const float*)d_in[1];
    const float* mask   = (const float*)d_in[2];
    const float* cen    = (const float*)d_in[3];
    float* ws  = (float*)d_ws;
    float* out = (float*)d_out;
    float* out_asg = out + 2 * B_ * C_ * D_;

    // zero the accumulator region (ksum, vsum, counts) every call
    hipMemsetAsync(ws + WS_KSUM_OFF, 0,
                   (size_t)(2 * B_ * C_ * D_ + B_ * C_) * sizeof(float), stream);

    normalize_centroids_k<<<1, 512, 0, stream>>>(cen, ws + WS_CNT_OFF);

    assign_k<<<(B_ * S_) / A_ROWS, A_THREADS, 0, stream>>>(
        keys, mask, ws + WS_CNT_OFF, out_asg);

    accum_k<<<(B_ * S_) / ACC_ROWS, ACC_THREADS, 0, stream>>>(
        keys, values, mask, out_asg,
        ws + WS_KSUM_OFF, ws + WS_VSUM_OFF, ws + WS_CNTS_OFF);

    finalize_k<<<(B_ * C_ * D_) / 256, 256, 0, stream>>>(ws, cen, out);
}

// Round 4
// 219.420 us; speedup vs baseline: 1.1067x; 1.0615x over previous
//
#include <hip/hip_runtime.h>

#define B_ 16
#define S_ 8192
#define D_ 128
#define C_ 64

// ---- legacy (atomic-fallback) ws layout, floats ----
#define WS_CNT_OFF   0
#define WS_KSUM_OFF  8192
#define WS_VSUM_OFF  (8192 + B_*C_*D_)
#define WS_CNTS_OFF  (8192 + 2*B_*C_*D_)

// ---- partial-store ws layout, floats ----
// [0,8192)                cnT
// [8192, 24576)           per-block counts   [256][64]
// [24576, 24576+4194304)  per-block partials [256][16384] (K:8192, V:8192)
#define WS2_CNT_OFF   0
#define WS2_CNTS_OFF  8192
#define WS2_PART_OFF  24576
#define WS2_NEEDED_BYTES ((size_t)(24576 + 256 * 16384) * 4)

__global__ void normalize_centroids_k(const float* __restrict__ cen,
                                      float* __restrict__ cnT) {
    int tid = threadIdx.x;          // 512 threads, 1 block
    int c = tid >> 3;               // 0..63
    int l = tid & 7;                // 8 lanes per centroid
    float4 v[4];
    float s = 0.f;
#pragma unroll
    for (int q = 0; q < 4; ++q) {
        v[q] = *(const float4*)&cen[c * D_ + l * 16 + q * 4];
        s += v[q].x * v[q].x + v[q].y * v[q].y + v[q].z * v[q].z + v[q].w * v[q].w;
    }
#pragma unroll
    for (int m = 1; m < 8; m <<= 1) s += __shfl_xor(s, m, 8);
    float n = fmaxf(sqrtf(s), 1e-12f);
#pragma unroll
    for (int q = 0; q < 4; ++q) {
        int d = l * 16 + q * 4;
        cnT[(d + 0) * C_ + c] = v[q].x / n;
        cnT[(d + 1) * C_ + c] = v[q].y / n;
        cnT[(d + 2) * C_ + c] = v[q].z / n;
        cnT[(d + 3) * C_ + c] = v[q].w / n;
    }
}

// ---------------- Kernel A: sims + argmax -> assignments (float) -----------
constexpr int A_THREADS = 256;
constexpr int A_TR = 4;                        // rows per thread
constexpr int A_ROWS = (A_THREADS / 8) * A_TR; // 128 rows per block

__global__ __launch_bounds__(A_THREADS, 4) void assign_k(
    const float* __restrict__ keys, const float* __restrict__ mask,
    const float* __restrict__ cnT_g, float* __restrict__ out_asg) {

    __shared__ float cnT[D_ * C_];   // 32 KB

    const int tid = threadIdx.x;
    for (int i = tid; i < D_ * C_; i += A_THREADS) cnT[i] = cnT_g[i];
    __syncthreads();

    const int tc  = tid & 7;          // cluster group: clusters tc*8 .. tc*8+7
    const int trt = tid >> 3;         // 0..31
    const size_t gr0 = (size_t)blockIdx.x * A_ROWS + (size_t)trt * A_TR;
    const float* kbase = keys + gr0 * D_;

    float acc[A_TR][8];
#pragma unroll
    for (int i = 0; i < A_TR; ++i)
#pragma unroll
        for (int j = 0; j < 8; ++j) acc[i][j] = 0.f;

    float4 kc[A_TR];
#pragma unroll
    for (int i = 0; i < A_TR; ++i)
        kc[i] = *(const float4*)(kbase + (size_t)i * D_);

    for (int d0 = 0; d0 < D_; d0 += 4) {
        float4 kn[A_TR];
        if (d0 + 4 < D_) {
#pragma unroll
            for (int i = 0; i < A_TR; ++i)
                kn[i] = *(const float4*)(kbase + (size_t)i * D_ + d0 + 4);
        }
#pragma unroll
        for (int dd = 0; dd < 4; ++dd) {
            const float4 c0 = *(const float4*)&cnT[(d0 + dd) * C_ + tc * 8];
            const float4 c1 = *(const float4*)&cnT[(d0 + dd) * C_ + tc * 8 + 4];
            const float cw[8] = {c0.x, c0.y, c0.z, c0.w, c1.x, c1.y, c1.z, c1.w};
#pragma unroll
            for (int i = 0; i < A_TR; ++i) {
                const float kv = dd == 0 ? kc[i].x : dd == 1 ? kc[i].y
                               : dd == 2 ? kc[i].z : kc[i].w;
#pragma unroll
                for (int j = 0; j < 8; ++j)
                    acc[i][j] = fmaf(kv, cw[j], acc[i][j]);
            }
        }
#pragma unroll
        for (int i = 0; i < A_TR; ++i) kc[i] = kn[i];
    }

    // per-row argmax across 8 tc lanes; first-max-index tie-break (jnp.argmax)
#pragma unroll
    for (int i = 0; i < A_TR; ++i) {
        float bv = acc[i][0];
        int bi = tc * 8;
#pragma unroll
        for (int j = 1; j < 8; ++j)
            if (acc[i][j] > bv) { bv = acc[i][j]; bi = tc * 8 + j; }
#pragma unroll
        for (int m = 1; m < 8; m <<= 1) {
            float ov = __shfl_xor(bv, m, 8);
            int   oi = __shfl_xor(bi, m, 8);
            if (ov > bv || (ov == bv && oi < bi)) { bv = ov; bi = oi; }
        }
        if (tc == 0) {
            float mv = mask[gr0 + i];
            out_asg[gr0 + i] = (float)((mv != 0.f) ? bi : 0);
        }
    }
}

// ---------------- Kernel B2: accumulate, conflict-free, partial-store ------
// 512 threads, 512 rows/block, grid 256 (1 block/CU).
// Wave w: row-in-group rw = w>>1, array = (w&1) ? V : K. Lane l owns dims
// {l, l+64} -> LDS atomic bank = l%32 (2-way, free). Loads are pure
// index functions, grouped x4 with a double buffer (8 loads in flight).
constexpr int B2_THREADS = 512;
constexpr int B2_ROWS    = 512;
constexpr int B2_NIT     = B2_ROWS / 4;   // 128 iterations of 4 rows
constexpr int B2_NGRP    = B2_NIT / 4;    // 32 groups

__global__ __launch_bounds__(B2_THREADS, 1) void accum2_k(
    const float* __restrict__ keys, const float* __restrict__ values,
    const float* __restrict__ mask, const float* __restrict__ out_asg,
    float* __restrict__ g_part, float* __restrict__ g_cnts) {

    __shared__ float accK[C_ * D_];   // 32 KB
    __shared__ float accV[C_ * D_];   // 32 KB
    __shared__ float cntL[C_];
    __shared__ short cid[B2_ROWS];

    const int tid = threadIdx.x;
    for (int i = tid; i < C_ * D_; i += B2_THREADS) { accK[i] = 0.f; accV[i] = 0.f; }
    if (tid < C_) cntL[tid] = 0.f;
    __syncthreads();

    const int bid = blockIdx.x;
    const int batch = bid >> 4;                 // 16 blocks per batch
    const int srow0 = (bid & 15) * B2_ROWS;
    const size_t rbase = (size_t)batch * S_ + srow0;

    // stage per-row cluster ids (sentinel C_ = masked out) + block counts
    {
        float mv = mask[rbase + tid];
        int a = (int)out_asg[rbase + tid];
        short s = (mv != 0.f) ? (short)a : (short)C_;
        cid[tid] = s;
        if (s < C_) atomicAdd(&cntL[s], 1.f);
    }
    __syncthreads();

    const int w   = tid >> 6;        // wave 0..7
    const int l   = tid & 63;
    const int rw  = w >> 1;          // row within 4-row group
    const int arr = w & 1;           // 0 = keys, 1 = values
    const float* src = (arr ? values : keys) + (rbase + rw) * (size_t)D_ + l;
    float* acc = arr ? accV : accK;

    float a0[4], a1[4];
#pragma unroll
    for (int q = 0; q < 4; ++q) {
        size_t o = (size_t)q * 4 * D_;
        a0[q] = src[o];
        a1[q] = src[o + 64];
    }
    for (int g = 0; g < B2_NGRP; ++g) {
        float b0[4], b1[4];
        if (g + 1 < B2_NGRP) {
#pragma unroll
            for (int q = 0; q < 4; ++q) {
                size_t o = (size_t)((g + 1) * 4 + q) * 4 * D_;
                b0[q] = src[o];
                b1[q] = src[o + 64];
            }
        }
#pragma unroll
        for (int q = 0; q < 4; ++q) {
            const int row = (g * 4 + q) * 4 + rw;
            const int a = cid[row];
            if (a < C_) {
                atomicAdd(&acc[a * D_ + l], a0[q]);
                atomicAdd(&acc[a * D_ + l + 64], a1[q]);
            }
        }
#pragma unroll
        for (int q = 0; q < 4; ++q) { a0[q] = b0[q]; a1[q] = b1[q]; }
    }
    __syncthreads();

    // non-atomic flush: per-block partial + counts
    float* pK = g_part + (size_t)bid * (2 * C_ * D_);
    float* pV = pK + C_ * D_;
    for (int i = tid * 4; i < C_ * D_; i += B2_THREADS * 4) {
        *(float4*)&pK[i] = *(const float4*)&accK[i];
        *(float4*)&pV[i] = *(const float4*)&accV[i];
    }
    if (tid < C_) g_cnts[bid * C_ + tid] = cntL[tid];
}

// ---------------- Kernel C2: reduce partials + finalize --------------------
__global__ void finalize2_k(const float* __restrict__ ws,
                            const float* __restrict__ cen,
                            float* __restrict__ out) {
    int idx = blockIdx.x * blockDim.x + threadIdx.x;   // < B*C*D
    const int b  = idx >> 13;            // /8192
    const int cd = idx & (C_ * D_ - 1);
    const int c  = cd >> 7;
    const float* part = ws + WS2_PART_OFF;
    const float* cnts = ws + WS2_CNTS_OFF;

    float ks = 0.f, vs = 0.f, n = 0.f;
#pragma unroll
    for (int p = 0; p < 16; ++p) {
        const size_t pb = (size_t)(b * 16 + p) * (2 * C_ * D_);
        ks += part[pb + cd];
        vs += part[pb + C_ * D_ + cd];
        n  += cnts[(b * 16 + p) * C_ + c];
    }
    float cc, cv;
    if (n > 0.f) {
        cc = ks / n;
        cv = vs / n;
    } else {
        cc = cen[cd];
        cv = 0.f;
    }
    out[idx] = cc;
    out[B_ * C_ * D_ + idx] = cv;
}

// ---------------- fallback (atomic) path, used only if ws too small -------
constexpr int ACC_THREADS = 512;
constexpr int ACC_ROWS   = 256;
constexpr int ACC_NIT    = ACC_ROWS / 8;

__global__ __launch_bounds__(ACC_THREADS, 2) void accum_k(
    const float* __restrict__ keys, const float* __restrict__ values,
    const float* __restrict__ mask, const float* __restrict__ out_asg,
    float* __restrict__ g_ksum, float* __restrict__ g_vsum,
    float* __restrict__ g_cnt) {

    __shared__ float accK[C_ * D_];
    __shared__ float accV[C_ * D_];
    __shared__ float cntL[C_];
    __shared__ short cid[ACC_ROWS];

    const int tid = threadIdx.x;
    for (int i = tid; i < C_ * D_; i += ACC_THREADS) { accK[i] = 0.f; accV[i] = 0.f; }
    if (tid < C_) cntL[tid] = 0.f;
    __syncthreads();

    const int bid = blockIdx.x;
    const int batch = bid >> 5;
    const int srow0 = (bid & 31) * ACC_ROWS;
    const size_t rbase = (size_t)batch * S_ + srow0;

    if (tid < ACC_ROWS) {
        float mv = mask[rbase + tid];
        int a = (int)out_asg[rbase + tid];
        short s = (mv != 0.f) ? (short)a : (short)C_;
        cid[tid] = s;
        if (s < C_) atomicAdd(&cntL[s], 1.f);
    }
    __syncthreads();

    const int r_off = tid >> 6;
    const int half  = (tid >> 5) & 1;
    const int c4    = tid & 31;
    const float* src = (half ? values : keys) + (rbase + r_off) * D_ + c4 * 4;
    float* acc = half ? accV : accK;

    for (int it = 0; it < ACC_NIT; ++it) {
        float4 cur = *(const float4*)(src + (size_t)it * 8 * D_);
        const int a = cid[it * 8 + r_off];
        if (a < C_) {
            float* p = &acc[a * D_ + c4 * 4];
            atomicAdd(p + 0, cur.x);
            atomicAdd(p + 1, cur.y);
            atomicAdd(p + 2, cur.z);
            atomicAdd(p + 3, cur.w);
        }
    }
    __syncthreads();

    float* gks = g_ksum + (size_t)batch * C_ * D_;
    float* gvs = g_vsum + (size_t)batch * C_ * D_;
    for (int i = tid; i < C_ * D_; i += ACC_THREADS) {
        atomicAdd(&gks[i], accK[i]);
        atomicAdd(&gvs[i], accV[i]);
    }
    if (tid < C_) atomicAdd(&g_cnt[batch * C_ + tid], cntL[tid]);
}

__global__ void finalize_k(const float* __restrict__ ws,
                           const float* __restrict__ cen,
                           float* __restrict__ out) {
    int idx = blockIdx.x * blockDim.x + threadIdx.x;
    const float* ksum = ws + WS_KSUM_OFF;
    const float* vsum = ws + WS_VSUM_OFF;
    const float* cnt  = ws + WS_CNTS_OFF;
    int bc = idx >> 7;
    int cd = idx & (C_ * D_ - 1);
    float n = cnt[bc];
    float cc, cv;
    if (n > 0.f) {
        cc = ksum[idx] / n;
        cv = vsum[idx] / n;
    } else {
        cc = cen[cd];
        cv = 0.f;
    }
    out[idx] = cc;
    out[B_ * C_ * D_ + idx] = cv;
}

extern "C" void kernel_launch(void* const* d_in, const int* in_sizes, int n_in,
                              void* d_out, int out_size, void* d_ws, size_t ws_size,
                              hipStream_t stream) {
    const float* keys   = (const float*)d_in[0];
    const float* values = (const float*)d_in[1];
    const float* mask   = (const float*)d_in[2];
    const float* cen    = (const float*)d_in[3];
    float* ws  = (float*)d_ws;
    float* out = (float*)d_out;
    float* out_asg = out + 2 * B_ * C_ * D_;

    normalize_centroids_k<<<1, 512, 0, stream>>>(cen, ws + WS2_CNT_OFF);

    assign_k<<<(B_ * S_) / A_ROWS, A_THREADS, 0, stream>>>(
        keys, mask, ws + WS2_CNT_OFF, out_asg);

    if (ws_size >= WS2_NEEDED_BYTES) {
        accum2_k<<<(B_ * S_) / B2_ROWS, B2_THREADS, 0, stream>>>(
            keys, values, mask, out_asg,
            ws + WS2_PART_OFF, ws + WS2_CNTS_OFF);
        finalize2_k<<<(B_ * C_ * D_) / 256, 256, 0, stream>>>(ws, cen, out);
    } else {
        hipMemsetAsync(ws + WS_KSUM_OFF, 0,
                       (size_t)(2 * B_ * C_ * D_ + B_ * C_) * sizeof(float), stream);
        accum_k<<<(B_ * S_) / ACC_ROWS, ACC_THREADS, 0, stream>>>(
            keys, values, mask, out_asg,
            ws + WS_KSUM_OFF, ws + WS_VSUM_OFF, ws + WS_CNTS_OFF);
        finalize_k<<<(B_ * C_ * D_) / 256, 256, 0, stream>>>(ws, cen, out);
    }
}

// Round 5
// 77.472 us; speedup vs baseline: 3.1344x; 2.8322x over previous
//
#include <hip/hip_runtime.h>

#define B_ 16
#define S_ 8192
#define D_ 128
#define C_ 64

// ---- legacy (atomic-fallback) ws layout, floats ----
#define WS_CNT_OFF   0
#define WS_KSUM_OFF  8192
#define WS_VSUM_OFF  (8192 + B_*C_*D_)
#define WS_CNTS_OFF  (8192 + 2*B_*C_*D_)

// ---- partial-store ws layout, floats ----
// [0,8192)                cnT
// [8192, 24576)           per-block counts   [256][64]
// [24576, 24576+4194304)  per-block partials [256][16384] (K:8192, V:8192)
#define WS2_CNT_OFF   0
#define WS2_CNTS_OFF  8192
#define WS2_PART_OFF  24576
#define WS2_NEEDED_BYTES ((size_t)(24576 + 256 * 16384) * 4)

__global__ void normalize_centroids_k(const float* __restrict__ cen,
                                      float* __restrict__ cnT) {
    int tid = threadIdx.x;          // 512 threads, 1 block
    int c = tid >> 3;               // 0..63
    int l = tid & 7;                // 8 lanes per centroid
    float4 v[4];
    float s = 0.f;
#pragma unroll
    for (int q = 0; q < 4; ++q) {
        v[q] = *(const float4*)&cen[c * D_ + l * 16 + q * 4];
        s += v[q].x * v[q].x + v[q].y * v[q].y + v[q].z * v[q].z + v[q].w * v[q].w;
    }
#pragma unroll
    for (int m = 1; m < 8; m <<= 1) s += __shfl_xor(s, m, 8);
    float n = fmaxf(sqrtf(s), 1e-12f);
#pragma unroll
    for (int q = 0; q < 4; ++q) {
        int d = l * 16 + q * 4;
        cnT[(d + 0) * C_ + c] = v[q].x / n;
        cnT[(d + 1) * C_ + c] = v[q].y / n;
        cnT[(d + 2) * C_ + c] = v[q].z / n;
        cnT[(d + 3) * C_ + c] = v[q].w / n;
    }
}

// ---------------- Kernel A: sims + argmax -> assignments (float) -----------
constexpr int A_THREADS = 256;
constexpr int A_TR = 4;                        // rows per thread
constexpr int A_ROWS = (A_THREADS / 8) * A_TR; // 128 rows per block

__global__ __launch_bounds__(A_THREADS, 4) void assign_k(
    const float* __restrict__ keys, const float* __restrict__ mask,
    const float* __restrict__ cnT_g, float* __restrict__ out_asg) {

    __shared__ float cnT[D_ * C_];   // 32 KB

    const int tid = threadIdx.x;
    for (int i = tid; i < D_ * C_; i += A_THREADS) cnT[i] = cnT_g[i];
    __syncthreads();

    const int tc  = tid & 7;          // cluster group: clusters tc*8 .. tc*8+7
    const int trt = tid >> 3;         // 0..31
    const size_t gr0 = (size_t)blockIdx.x * A_ROWS + (size_t)trt * A_TR;
    const float* kbase = keys + gr0 * D_;

    float acc[A_TR][8];
#pragma unroll
    for (int i = 0; i < A_TR; ++i)
#pragma unroll
        for (int j = 0; j < 8; ++j) acc[i][j] = 0.f;

    float4 kc[A_TR];
#pragma unroll
    for (int i = 0; i < A_TR; ++i)
        kc[i] = *(const float4*)(kbase + (size_t)i * D_);

    for (int d0 = 0; d0 < D_; d0 += 4) {
        float4 kn[A_TR];
        if (d0 + 4 < D_) {
#pragma unroll
            for (int i = 0; i < A_TR; ++i)
                kn[i] = *(const float4*)(kbase + (size_t)i * D_ + d0 + 4);
        }
#pragma unroll
        for (int dd = 0; dd < 4; ++dd) {
            const float4 c0 = *(const float4*)&cnT[(d0 + dd) * C_ + tc * 8];
            const float4 c1 = *(const float4*)&cnT[(d0 + dd) * C_ + tc * 8 + 4];
            const float cw[8] = {c0.x, c0.y, c0.z, c0.w, c1.x, c1.y, c1.z, c1.w};
#pragma unroll
            for (int i = 0; i < A_TR; ++i) {
                const float kv = dd == 0 ? kc[i].x : dd == 1 ? kc[i].y
                               : dd == 2 ? kc[i].z : kc[i].w;
#pragma unroll
                for (int j = 0; j < 8; ++j)
                    acc[i][j] = fmaf(kv, cw[j], acc[i][j]);
            }
        }
#pragma unroll
        for (int i = 0; i < A_TR; ++i) kc[i] = kn[i];
    }

    // per-row argmax across 8 tc lanes; first-max-index tie-break (jnp.argmax)
#pragma unroll
    for (int i = 0; i < A_TR; ++i) {
        float bv = acc[i][0];
        int bi = tc * 8;
#pragma unroll
        for (int j = 1; j < 8; ++j)
            if (acc[i][j] > bv) { bv = acc[i][j]; bi = tc * 8 + j; }
#pragma unroll
        for (int m = 1; m < 8; m <<= 1) {
            float ov = __shfl_xor(bv, m, 8);
            int   oi = __shfl_xor(bi, m, 8);
            if (ov > bv || (ov == bv && oi < bi)) { bv = ov; bi = oi; }
        }
        if (tc == 0) {
            float mv = mask[gr0 + i];
            out_asg[gr0 + i] = (float)((mv != 0.f) ? bi : 0);
        }
    }
}

// ---------------- Kernel B3: accumulate, NON-ATOMIC private regions --------
// 512 threads = 8 waves: (arr K/V) x (dim-half h) x (row-half r).
// Each wave owns a private [65][64] f32 LDS region (slot 64 = dummy sink for
// masked/merged rows) -> plain ds_read/add/ds_write RMW, no atomics.
// Rows processed in groups of 8; duplicate cluster ids within a group are
// merged in-register so the 8 RMWs hit distinct addresses.
constexpr int B3_THREADS   = 512;
constexpr int B3_ROWS      = 512;          // rows per block
constexpr int B3_RPW       = B3_ROWS / 2;  // rows per wave (row-half)
constexpr int B3_NGRP      = B3_RPW / 8;   // 32 groups of 8 rows
constexpr int REG_STRIDE   = (C_ + 1) * 64;  // 4160 floats per region

__global__ __launch_bounds__(B3_THREADS, 1) void accum3_k(
    const float* __restrict__ keys, const float* __restrict__ values,
    const float* __restrict__ mask, const float* __restrict__ out_asg,
    float* __restrict__ g_part, float* __restrict__ g_cnts) {

    __shared__ float acc[8 * REG_STRIDE];   // 130 KB
    __shared__ float cntL[C_];
    __shared__ short cid[B3_ROWS];

    const int tid = threadIdx.x;
    for (int i = tid; i < 8 * REG_STRIDE; i += B3_THREADS) acc[i] = 0.f;
    if (tid < C_) cntL[tid] = 0.f;
    __syncthreads();

    const int bid = blockIdx.x;
    const int batch = bid >> 4;                 // 16 blocks per batch
    const int srow0 = (bid & 15) * B3_ROWS;
    const size_t rbase = (size_t)batch * S_ + srow0;

    // stage per-row cluster ids (sentinel C_ = masked out) + block counts
    {
        float mv = mask[rbase + tid];
        int a = (int)out_asg[rbase + tid];
        short s = (mv != 0.f) ? (short)a : (short)C_;
        cid[tid] = s;
        if (s < (short)C_) atomicAdd(&cntL[s], 1.f);
    }
    __syncthreads();

    const int w   = tid >> 6;
    const int l   = tid & 63;
    const int arr = w & 1;           // 0 = keys, 1 = values
    const int h   = (w >> 1) & 1;    // dim half
    const int r   = w >> 2;          // row half
    const float* src = (arr ? values : keys)
                       + (rbase + (size_t)r * B3_RPW) * D_ + h * 64 + l;
    float* aw = acc + ((arr * 2 + h) * 2 + r) * REG_STRIDE;
    const short* cbase = cid + r * B3_RPW;

    float v[8], vn[8];
#pragma unroll
    for (int j = 0; j < 8; ++j) v[j] = src[(size_t)j * D_];

    for (int g = 0; g < B3_NGRP; ++g) {
        if (g + 1 < B3_NGRP) {
#pragma unroll
            for (int j = 0; j < 8; ++j)
                vn[j] = src[(size_t)((g + 1) * 8 + j) * D_];
        }
        // 8 cluster ids via one 16B broadcast read
        int4 ci = *(const int4*)(cbase + g * 8);
        int c8[8];
        c8[0] = ci.x & 0xffff;  c8[1] = ci.x >> 16;
        c8[2] = ci.y & 0xffff;  c8[3] = ci.y >> 16;
        c8[4] = ci.z & 0xffff;  c8[5] = ci.z >> 16;
        c8[6] = ci.w & 0xffff;  c8[7] = ci.w >> 16;

        // merge duplicate cids into the first occurrence; duplicates -> dummy
#pragma unroll
        for (int j = 1; j < 8; ++j) {
            bool done = false;
#pragma unroll
            for (int i = 0; i < j; ++i) {
                bool eq = (c8[i] == c8[j]);
                v[i] += (eq && !done) ? v[j] : 0.f;
                done = done || eq;
            }
            c8[j] = done ? C_ : c8[j];
        }

        // batched non-atomic RMW: 8 reads, then 8 writes (distinct addresses)
        float old[8];
#pragma unroll
        for (int j = 0; j < 8; ++j) old[j] = aw[c8[j] * 64 + l];
#pragma unroll
        for (int j = 0; j < 8; ++j) aw[c8[j] * 64 + l] = old[j] + v[j];

#pragma unroll
        for (int j = 0; j < 8; ++j) v[j] = vn[j];
    }
    __syncthreads();

    // flush: sum the two row-half regions, store per-block partial
    float* pb = g_part + (size_t)bid * (2 * C_ * D_);
    for (int i = tid * 4; i < 2 * C_ * D_; i += B3_THREADS * 4) {
        const int ar = i >> 13;
        const int cd = i & (C_ * D_ - 1);
        const int c  = cd >> 7;
        const int d  = cd & 127;
        const int hh = d >> 6;
        const int dl = d & 63;
        const float* r0 = acc + ((ar * 2 + hh) * 2 + 0) * REG_STRIDE + c * 64 + dl;
        const float* r1 = acc + ((ar * 2 + hh) * 2 + 1) * REG_STRIDE + c * 64 + dl;
        float4 s0 = *(const float4*)r0;
        float4 s1 = *(const float4*)r1;
        float4 o;
        o.x = s0.x + s1.x; o.y = s0.y + s1.y;
        o.z = s0.z + s1.z; o.w = s0.w + s1.w;
        *(float4*)&pb[i] = o;
    }
    if (tid < C_) g_cnts[bid * C_ + tid] = cntL[tid];
}

// ---------------- Kernel C2: reduce partials + finalize --------------------
__global__ void finalize2_k(const float* __restrict__ ws,
                            const float* __restrict__ cen,
                            float* __restrict__ out) {
    int idx = blockIdx.x * blockDim.x + threadIdx.x;   // < B*C*D
    const int b  = idx >> 13;            // /8192
    const int cd = idx & (C_ * D_ - 1);
    const int c  = cd >> 7;
    const float* part = ws + WS2_PART_OFF;
    const float* cnts = ws + WS2_CNTS_OFF;

    float ks = 0.f, vs = 0.f, n = 0.f;
#pragma unroll
    for (int p = 0; p < 16; ++p) {
        const size_t pb = (size_t)(b * 16 + p) * (2 * C_ * D_);
        ks += part[pb + cd];
        vs += part[pb + C_ * D_ + cd];
        n  += cnts[(b * 16 + p) * C_ + c];
    }
    float cc, cv;
    if (n > 0.f) {
        cc = ks / n;
        cv = vs / n;
    } else {
        cc = cen[cd];
        cv = 0.f;
    }
    out[idx] = cc;
    out[B_ * C_ * D_ + idx] = cv;
}

// ---------------- fallback (atomic) path, used only if ws too small -------
constexpr int ACC_THREADS = 512;
constexpr int ACC_ROWS   = 256;
constexpr int ACC_NIT    = ACC_ROWS / 8;

__global__ __launch_bounds__(ACC_THREADS, 2) void accum_k(
    const float* __restrict__ keys, const float* __restrict__ values,
    const float* __restrict__ mask, const float* __restrict__ out_asg,
    float* __restrict__ g_ksum, float* __restrict__ g_vsum,
    float* __restrict__ g_cnt) {

    __shared__ float accK[C_ * D_];
    __shared__ float accV[C_ * D_];
    __shared__ float cntL[C_];
    __shared__ short cid[ACC_ROWS];

    const int tid = threadIdx.x;
    for (int i = tid; i < C_ * D_; i += ACC_THREADS) { accK[i] = 0.f; accV[i] = 0.f; }
    if (tid < C_) cntL[tid] = 0.f;
    __syncthreads();

    const int bid = blockIdx.x;
    const int batch = bid >> 5;
    const int srow0 = (bid & 31) * ACC_ROWS;
    const size_t rbase = (size_t)batch * S_ + srow0;

    if (tid < ACC_ROWS) {
        float mv = mask[rbase + tid];
        int a = (int)out_asg[rbase + tid];
        short s = (mv != 0.f) ? (short)a : (short)C_;
        cid[tid] = s;
        if (s < C_) atomicAdd(&cntL[s], 1.f);
    }
    __syncthreads();

    const int r_off = tid >> 6;
    const int half  = (tid >> 5) & 1;
    const int c4    = tid & 31;
    const float* src = (half ? values : keys) + (rbase + r_off) * D_ + c4 * 4;
    float* acc = half ? accV : accK;

    for (int it = 0; it < ACC_NIT; ++it) {
        float4 cur = *(const float4*)(src + (size_t)it * 8 * D_);
        const int a = cid[it * 8 + r_off];
        if (a < C_) {
            float* p = &acc[a * D_ + c4 * 4];
            atomicAdd(p + 0, cur.x);
            atomicAdd(p + 1, cur.y);
            atomicAdd(p + 2, cur.z);
            atomicAdd(p + 3, cur.w);
        }
    }
    __syncthreads();

    float* gks = g_ksum + (size_t)batch * C_ * D_;
    float* gvs = g_vsum + (size_t)batch * C_ * D_;
    for (int i = tid; i < C_ * D_; i += ACC_THREADS) {
        atomicAdd(&gks[i], accK[i]);
        atomicAdd(&gvs[i], accV[i]);
    }
    if (tid < C_) atomicAdd(&g_cnt[batch * C_ + tid], cntL[tid]);
}

__global__ void finalize_k(const float* __restrict__ ws,
                           const float* __restrict__ cen,
                           float* __restrict__ out) {
    int idx = blockIdx.x * blockDim.x + threadIdx.x;
    const float* ksum = ws + WS_KSUM_OFF;
    const float* vsum = ws + WS_VSUM_OFF;
    const float* cnt  = ws + WS_CNTS_OFF;
    int bc = idx >> 7;
    int cd = idx & (C_ * D_ - 1);
    float n = cnt[bc];
    float cc, cv;
    if (n > 0.f) {
        cc = ksum[idx] / n;
        cv = vsum[idx] / n;
    } else {
        cc = cen[cd];
        cv = 0.f;
    }
    out[idx] = cc;
    out[B_ * C_ * D_ + idx] = cv;
}

extern "C" void kernel_launch(void* const* d_in, const int* in_sizes, int n_in,
                              void* d_out, int out_size, void* d_ws, size_t ws_size,
                              hipStream_t stream) {
    const float* keys   = (const float*)d_in[0];
    const float* values = (const float*)d_in[1];
    const float* mask   = (const float*)d_in[2];
    const float* cen    = (const float*)d_in[3];
    float* ws  = (float*)d_ws;
    float* out = (float*)d_out;
    float* out_asg = out + 2 * B_ * C_ * D_;

    normalize_centroids_k<<<1, 512, 0, stream>>>(cen, ws + WS2_CNT_OFF);

    assign_k<<<(B_ * S_) / A_ROWS, A_THREADS, 0, stream>>>(
        keys, mask, ws + WS2_CNT_OFF, out_asg);

    if (ws_size >= WS2_NEEDED_BYTES) {
        accum3_k<<<(B_ * S_) / B3_ROWS, B3_THREADS, 0, stream>>>(
            keys, values, mask, out_asg,
            ws + WS2_PART_OFF, ws + WS2_CNTS_OFF);
        finalize2_k<<<(B_ * C_ * D_) / 256, 256, 0, stream>>>(ws, cen, out);
    } else {
        hipMemsetAsync(ws + WS_KSUM_OFF, 0,
                       (size_t)(2 * B_ * C_ * D_ + B_ * C_) * sizeof(float), stream);
        accum_k<<<(B_ * S_) / ACC_ROWS, ACC_THREADS, 0, stream>>>(
            keys, values, mask, out_asg,
            ws + WS_KSUM_OFF, ws + WS_VSUM_OFF, ws + WS_CNTS_OFF);
        finalize_k<<<(B_ * C_ * D_) / 256, 256, 0, stream>>>(ws, cen, out);
    }
}